// Round 4
// baseline (469.975 us; speedup 1.0000x reference)
//
#include <hip/hip_runtime.h>

typedef unsigned short u16;
typedef __attribute__((ext_vector_type(8))) short bf16x8;   // 8 bf16 = 4 VGPR
typedef __attribute__((ext_vector_type(4))) float f32x4;

#define BATCH 16
#define SEQ   2048
#define EMBD  512
#define NOUT  8
#define QB    64
#define KVB   64
#define NT    (SEQ/KVB)      // 32 KV tiles

#define GLOBAL_AS __attribute__((address_space(1)))
#define LDS_AS    __attribute__((address_space(3)))

__device__ __forceinline__ u16 f2bf(float f){          // f32 -> bf16 RNE
  unsigned u = __float_as_uint(f);
  u += 0x7fffu + ((u >> 16) & 1u);
  return (u16)(u >> 16);
}

__device__ __forceinline__ void gload_lds16(const void* g, void* l){
  __builtin_amdgcn_global_load_lds((const GLOBAL_AS unsigned int*)g,
                                   (LDS_AS unsigned int*)l, 16, 0, 0);
}

// ---------------------------------------------------------------------------
// Kernel 0: E[b*SEQ+n][e] = bf16(table[x[b,n]][e]); padding_idx==0 -> zeros.
// ---------------------------------------------------------------------------
__global__ __launch_bounds__(512) void k_embed(const int* __restrict__ x,
                                               const float* __restrict__ tab,
                                               u16* __restrict__ E){
  int r = blockIdx.x * 8 + (threadIdx.x >> 6);   // 0..32767
  int l = threadIdx.x & 63;
  int idx = x[r];
  float4 a = make_float4(0.f,0.f,0.f,0.f), c = a;
  if (idx != 0){
    const float4* src = (const float4*)(tab + (size_t)idx * EMBD);
    a = src[l*2]; c = src[l*2+1];
  }
  bf16x8 v;
  v[0]=f2bf(a.x); v[1]=f2bf(a.y); v[2]=f2bf(a.z); v[3]=f2bf(a.w);
  v[4]=f2bf(c.x); v[5]=f2bf(c.y); v[6]=f2bf(c.z); v[7]=f2bf(c.w);
  *(bf16x8*)(E + (size_t)r * EMBD + l*8) = v;
}

// ---------------------------------------------------------------------------
// Kernel 1: flash attention (Q=K=V=E) + per-Q-tile column max.
// 512 thr (8 waves) per (batch, 64-row Q tile). KVB=64.
// - K: single-buffer LDS via global_load_lds (stage(t+1) issued post-B2,
//   covered by PV, drained at next B0); src pre-swizzled (chunk ^ row&7).
// - QKT split qg=w&1 (32 q rows) x kgi=w>>1 (16 tokens): only 2 waves share
//   each kb fragment (halves kb LDS traffic); qf[2][16] = 128 VGPR.
// - V: register transpose into wave-private Vt (R2-proven path, at LDS floor).
// - 3 barriers/tile; setprio around MFMA clusters; alpha-skip rescale.
// ---------------------------------------------------------------------------
__global__ __launch_bounds__(512, 2) void k_attn(const u16* __restrict__ E,
                                                 float* __restrict__ part){
  __shared__ u16   Klds[KVB * EMBD];     // 64 KB, 16B-chunk swizzled
  __shared__ float Sbuf[QB][68];         // 17.4 KB
  __shared__ u16   Ps[QB][72];           // 9.2 KB
  __shared__ u16   Vt[8 * 64 * 64];      // 64 KB: per-wave [64 e][64 tok] swz
  __shared__ float m_lds[QB], l_lds[QB], a_lds[QB];

  const int tid = threadIdx.x;
  const int w   = tid >> 6;              // wave 0..7
  const int l   = tid & 63;
  const int l15 = l & 15, lg = l >> 4;

  // XCD-affine decode: batch b's 32 q-tiles land on XCD (b&7).
  const int blk  = blockIdx.x;
  const int xcd  = blk & 7;
  const int slot = blk >> 3;             // 0..63
  const int b    = xcd + 8 * (slot >> 5);
  const int qt   = slot & 31;
  const size_t ebase = (size_t)b * SEQ * EMBD;

  // ---- Q fragments: rows [qt*64+qg*32, +32), full D (128 VGPR) ----
  const int qg  = w & 1;                 // q half: rows qg*32..+32
  const int kgi = w >> 1;                // token block: kgi*16..+16
  bf16x8 qf[2][16];
  #pragma unroll
  for (int ip = 0; ip < 2; ip++){
    const u16* qp = E + ebase
        + (size_t)(qt*QB + qg*32 + ip*16 + l15) * EMBD + lg*8;
    #pragma unroll
    for (int es = 0; es < 16; es++) qf[ip][es] = *(const bf16x8*)(qp + es*32);
  }

  f32x4 acc[4][4];                       // O[ip*16+lg*4+rr][w*64+jp*16+l15]
  #pragma unroll
  for (int ip = 0; ip < 4; ip++)
    #pragma unroll
    for (int jp = 0; jp < 4; jp++) acc[ip][jp] = (f32x4){0.f,0.f,0.f,0.f};

  if (tid < QB){ m_lds[tid] = -INFINITY; l_lds[tid] = 0.f; }

  // stage K rows r=w*8+i; LDS dest wave-uniform base (+lane*16B implicit);
  // global src chunk pre-swizzled l ^ (r&7) so logical chunk c sits at c^(r&7)
  #define STAGE(tile_)                                                       \
    { const int kk0 = (tile_) * KVB;                                         \
      _Pragma("unroll")                                                      \
      for (int i = 0; i < 8; i++){                                           \
        const int r = w*8 + i;                                               \
        const u16* src = E + ebase + (size_t)(kk0 + r) * EMBD                \
                           + ((l ^ (r & 7)) * 8);                            \
        gload_lds16(src, Klds + (size_t)r * EMBD);                           \
      } }

  STAGE(0)

  const int quad = l & 15, c8h = l >> 4;
  const int e7 = l15 & 7;

  for (int t = 0; t < NT; t++){
    const int k0 = t * KVB;
    __syncthreads();                     // B0: stage(t) drained; bufs free

    // ---- issue V row loads (consumed by Vt transpose after QKT) ----
    bf16x8 vr[2][4];
    #pragma unroll
    for (int h = 0; h < 2; h++){
      const int c8 = c8h + h*4;          // e-chunk 0..7 in wave's 64-e slice
      const u16* vp = E + ebase + (size_t)(k0 + quad*4) * EMBD + w*64 + c8*8;
      vr[h][0] = *(const bf16x8*)(vp);
      vr[h][1] = *(const bf16x8*)(vp +   EMBD);
      vr[h][2] = *(const bf16x8*)(vp + 2*EMBD);
      vr[h][3] = *(const bf16x8*)(vp + 3*EMBD);
    }

    // ---- QK^T: S[qg*32..+32][kgi*16..+16] ----
    f32x4 s0 = (f32x4){0.f,0.f,0.f,0.f}, s1 = s0;
    {
      const u16* kbase = &Klds[(kgi*16 + l15) * EMBD];
      __builtin_amdgcn_s_setprio(1);
      #pragma unroll
      for (int es = 0; es < 16; es++){
        const int cst = (es*4 + lg) ^ e7;
        bf16x8 kb = *(const bf16x8*)(kbase + cst*8);
        s0 = __builtin_amdgcn_mfma_f32_16x16x32_bf16(qf[0][es], kb, s0, 0,0,0);
        s1 = __builtin_amdgcn_mfma_f32_16x16x32_bf16(qf[1][es], kb, s1, 0,0,0);
      }
      __builtin_amdgcn_s_setprio(0);
    }
    {
      const int col = kgi*16 + l15, row0 = qg*32 + lg*4;
      #pragma unroll
      for (int rr = 0; rr < 4; rr++){
        Sbuf[row0 + rr][col]      = s0[rr];
        Sbuf[row0 + 16 + rr][col] = s1[rr];
      }
    }

    // ---- V transpose into wave-private Vt (b64 writes, floor-phased) ----
    #pragma unroll
    for (int h = 0; h < 2; h++){
      const int c8 = c8h + h*4;
      #pragma unroll
      for (int i = 0; i < 8; i++){
        const int el = c8*8 + i;                       // e_local 0..63
        const int ch = (quad >> 1) ^ (el & 7);         // swizzled 16B chunk
        short4 sv; sv.x = vr[h][0][i]; sv.y = vr[h][1][i];
                   sv.z = vr[h][2][i]; sv.w = vr[h][3][i];
        *(short4*)&Vt[(size_t)w*4096 + el*64 + ch*8 + (quad&1)*4] = sv;
      }
    }

    __syncthreads();                     // B1: Sbuf + Vt complete

    // ---- online softmax: thread = (row=tid>>3, cg=tid&7), 8 tok each ----
    {
      const int row = tid >> 3, cg = tid & 7;
      f32x4 sa = *(f32x4*)&Sbuf[row][cg*8];
      f32x4 sb = *(f32x4*)&Sbuf[row][cg*8 + 4];
      float mx = fmaxf(fmaxf(fmaxf(sa[0],sa[1]), fmaxf(sa[2],sa[3])),
                       fmaxf(fmaxf(sb[0],sb[1]), fmaxf(sb[2],sb[3])));
      #pragma unroll
      for (int d = 1; d < 8; d <<= 1) mx = fmaxf(mx, __shfl_xor(mx, d));
      const float mold = m_lds[row], lold = l_lds[row];
      const float mnew = fmaxf(mold, mx);
      float pp[8];
      #pragma unroll
      for (int i = 0; i < 4; i++) pp[i]   = __expf(sa[i] - mnew);
      #pragma unroll
      for (int i = 0; i < 4; i++) pp[4+i] = __expf(sb[i] - mnew);
      float sum = ((pp[0]+pp[1])+(pp[2]+pp[3])) + ((pp[4]+pp[5])+(pp[6]+pp[7]));
      #pragma unroll
      for (int d = 1; d < 8; d <<= 1) sum += __shfl_xor(sum, d);
      const float alpha = __expf(mold - mnew);   // -inf -> 0 on first tile
      if (cg == 0){
        m_lds[row] = mnew;
        l_lds[row] = lold * alpha + sum;
        a_lds[row] = alpha;
      }
      bf16x8 pv;
      #pragma unroll
      for (int i = 0; i < 8; i++) pv[i] = (short)f2bf(pp[i]);
      *(bf16x8*)&Ps[row][cg*8] = pv;
    }

    __syncthreads();                     // B2: Ps + alpha ready

    // ---- stage K(t+1): overlaps PV, drained at next B0 ----
    if (t + 1 < NT) STAGE(t + 1)

    // ---- rescale O (skip when all alpha==1), then O += P V ----
    {
      f32x4 al[4];
      int need = 0;
      #pragma unroll
      for (int ip = 0; ip < 4; ip++){
        al[ip] = *(f32x4*)&a_lds[ip*16 + lg*4];
        need |= (al[ip][0] != 1.f) | (al[ip][1] != 1.f) |
                (al[ip][2] != 1.f) | (al[ip][3] != 1.f);
      }
      if (__any(need)){
        #pragma unroll
        for (int ip = 0; ip < 4; ip++)
          #pragma unroll
          for (int jp = 0; jp < 4; jp++)
            #pragma unroll
            for (int rr = 0; rr < 4; rr++) acc[ip][jp][rr] *= al[ip][rr];
      }
    }
    #pragma unroll
    for (int kt = 0; kt < 2; kt++){
      bf16x8 pa[4], vb[4];
      #pragma unroll
      for (int ip = 0; ip < 4; ip++)
        pa[ip] = *(const bf16x8*)&Ps[ip*16 + l15][kt*32 + lg*8];
      #pragma unroll
      for (int jp = 0; jp < 4; jp++){
        const int el = jp*16 + l15;                    // e_local
        const int ch = (kt*4 + lg) ^ (el & 7);
        vb[jp] = *(const bf16x8*)&Vt[(size_t)w*4096 + el*64 + ch*8];
      }
      __builtin_amdgcn_s_setprio(1);
      #pragma unroll
      for (int ip = 0; ip < 4; ip++)
        #pragma unroll
        for (int jp = 0; jp < 4; jp++)
          acc[ip][jp] = __builtin_amdgcn_mfma_f32_16x16x32_bf16(
                            pa[ip], vb[jp], acc[ip][jp], 0, 0, 0);
      __builtin_amdgcn_s_setprio(0);
    }
  }

  __syncthreads();
  // ---- epilogue: 1/l scaling, column max over 64 q-rows, write partial ----
  #pragma unroll
  for (int ip = 0; ip < 4; ip++){
    f32x4 lv = *(f32x4*)&l_lds[ip*16 + lg*4];
    f32x4 inv;
    #pragma unroll
    for (int rr = 0; rr < 4; rr++) inv[rr] = 1.f / lv[rr];
    #pragma unroll
    for (int jp = 0; jp < 4; jp++)
      #pragma unroll
      for (int rr = 0; rr < 4; rr++) acc[ip][jp][rr] *= inv[rr];
  }
  #pragma unroll
  for (int jp = 0; jp < 4; jp++){
    float cm = -INFINITY;
    #pragma unroll
    for (int ip = 0; ip < 4; ip++)
      #pragma unroll
      for (int rr = 0; rr < 4; rr++) cm = fmaxf(cm, acc[ip][jp][rr]);
    cm = fmaxf(cm, __shfl_xor(cm, 16));
    cm = fmaxf(cm, __shfl_xor(cm, 32));
    if (lg == 0)
      part[(size_t)(b*32 + qt) * EMBD + w*64 + jp*16 + l15] = cm;
  }
}

// ---------------------------------------------------------------------------
// Kernel 2: pooled[b][e] = max over 32 q-tiles; out[b][o] = pooled.W[o] + b[o]
// ---------------------------------------------------------------------------
__global__ __launch_bounds__(512) void k_final(const float* __restrict__ part,
                                               const float* __restrict__ Wm,
                                               const float* __restrict__ bias,
                                               float* __restrict__ out){
  __shared__ float pooled[EMBD];
  const int b = blockIdx.x, tid = threadIdx.x;
  float mx = -INFINITY;
  const float* pb = part + (size_t)b * 32 * EMBD + tid;
  #pragma unroll
  for (int qt = 0; qt < 32; qt++) mx = fmaxf(mx, pb[qt * EMBD]);
  pooled[tid] = mx;
  __syncthreads();
  const int w = tid >> 6, l = tid & 63;     // w = output index (8 waves)
  float sum = 0.f;
  #pragma unroll
  for (int m = 0; m < 8; m++)
    sum += pooled[l + m*64] * Wm[w*EMBD + l + m*64];
  #pragma unroll
  for (int d = 1; d < 64; d <<= 1) sum += __shfl_xor(sum, d);
  if (l == 0) out[b * NOUT + w] = sum + bias[w];
}

// ---------------------------------------------------------------------------
extern "C" void kernel_launch(void* const* d_in, const int* in_sizes, int n_in,
                              void* d_out, int out_size, void* d_ws, size_t ws_size,
                              hipStream_t stream){
  const int*   x    = (const int*)  d_in[0];   // [16,2048]
  const float* tab  = (const float*)d_in[1];   // [32000,512]
  const float* Wm   = (const float*)d_in[2];   // [8,512]
  const float* bias = (const float*)d_in[3];   // [8]
  float* out = (float*)d_out;                  // [16,8]

  // ws: E bf16 [16*2048,512] = 32MB, then partials [16][32][512] f32 = 1MB
  u16*   E    = (u16*)d_ws;
  float* part = (float*)((char*)d_ws + (size_t)32 * 1024 * 1024);

  k_embed<<<BATCH*SEQ/8, 512, 0, stream>>>(x, tab, E);
  k_attn <<<BATCH*(SEQ/QB), 512, 0, stream>>>(E, part);
  k_final<<<BATCH, 512, 0, stream>>>(part, Wm, bias, out);
}

// Round 5
// 286.854 us; speedup vs baseline: 1.6384x; 1.6384x over previous
//
#include <hip/hip_runtime.h>

typedef unsigned short u16;
typedef __attribute__((ext_vector_type(8))) short bf16x8;   // 8 bf16 = 4 VGPR
typedef __attribute__((ext_vector_type(4))) float f32x4;

#define BATCH 16
#define SEQ   2048
#define EMBD  512
#define NOUT  8
#define QB    64
#define KVB   64
#define NT    (SEQ/KVB)      // 32 KV tiles

#define GLOBAL_AS __attribute__((address_space(1)))
#define LDS_AS    __attribute__((address_space(3)))

__device__ __forceinline__ u16 f2bf(float f){          // f32 -> bf16 RNE
  unsigned u = __float_as_uint(f);
  u += 0x7fffu + ((u >> 16) & 1u);
  return (u16)(u >> 16);
}

__device__ __forceinline__ void gload_lds16(const void* g, void* l){
  __builtin_amdgcn_global_load_lds((const GLOBAL_AS unsigned int*)g,
                                   (LDS_AS unsigned int*)l, 16, 0, 0);
}

// ---------------------------------------------------------------------------
// Kernel 0: E[b*SEQ+n][e] = bf16(table[x[b,n]][e]); padding_idx==0 -> zeros.
// ---------------------------------------------------------------------------
__global__ __launch_bounds__(512) void k_embed(const int* __restrict__ x,
                                               const float* __restrict__ tab,
                                               u16* __restrict__ E){
  int r = blockIdx.x * 8 + (threadIdx.x >> 6);   // 0..32767
  int l = threadIdx.x & 63;
  int idx = x[r];
  float4 a = make_float4(0.f,0.f,0.f,0.f), c = a;
  if (idx != 0){
    const float4* src = (const float4*)(tab + (size_t)idx * EMBD);
    a = src[l*2]; c = src[l*2+1];
  }
  bf16x8 v;
  v[0]=f2bf(a.x); v[1]=f2bf(a.y); v[2]=f2bf(a.z); v[3]=f2bf(a.w);
  v[4]=f2bf(c.x); v[5]=f2bf(c.y); v[6]=f2bf(c.z); v[7]=f2bf(c.w);
  *(bf16x8*)(E + (size_t)r * EMBD + l*8) = v;
}

// ---------------------------------------------------------------------------
// Kernel 1: flash attention (Q=K=V=E) + per-Q-tile column max.
// EXACT R2 structure (proven 288 us, no spills: qf[16]=64 regs, iq x jq
// QKT split, wave-private Vt) plus register-neutral tweaks only:
//  - s_setprio(1) around MFMA clusters (T5)
//  - alpha-skip rescale (running max stabilizes -> alpha==1.0 exactly)
//  - STAGE(t+1) issued right after B1 (QKT reads done) instead of after B2
// ---------------------------------------------------------------------------
__global__ __launch_bounds__(512, 2) void k_attn(const u16* __restrict__ E,
                                                 float* __restrict__ part){
  __shared__ u16   Klds[KVB * EMBD];     // 64 KB, 16B-chunk swizzled
  __shared__ float Sbuf[QB][68];         // 17.4 KB
  __shared__ u16   Ps[QB][72];           // 9.2 KB
  __shared__ u16   Vt[8 * 64 * 64];      // 64 KB: per-wave [64 e][64 tok] swz
  __shared__ float m_lds[QB], l_lds[QB], a_lds[QB];

  const int tid = threadIdx.x;
  const int w   = tid >> 6;              // wave 0..7
  const int l   = tid & 63;
  const int l15 = l & 15, lg = l >> 4;

  // XCD-affine decode: batch b's 32 q-tiles land on XCD (b&7).
  const int blk  = blockIdx.x;
  const int xcd  = blk & 7;
  const int slot = blk >> 3;             // 0..63
  const int b    = xcd + 8 * (slot >> 5);
  const int qt   = slot & 31;
  const size_t ebase = (size_t)b * SEQ * EMBD;

  // ---- Q fragments: wave's 16 q-rows (iq), full D -> 64 VGPR ----
  const int iq = w >> 1, jq = w & 1;
  const u16* qp = E + ebase + (size_t)(qt*QB + iq*16 + l15) * EMBD + lg*8;
  bf16x8 qf[16];
  #pragma unroll
  for (int ks = 0; ks < 16; ks++) qf[ks] = *(const bf16x8*)(qp + ks*32);

  f32x4 acc[4][4];                       // O[ip*16+lg*4+rr][w*64+jp*16+l15]
  #pragma unroll
  for (int ip = 0; ip < 4; ip++)
    #pragma unroll
    for (int jp = 0; jp < 4; jp++) acc[ip][jp] = (f32x4){0.f,0.f,0.f,0.f};

  if (tid < QB){ m_lds[tid] = -INFINITY; l_lds[tid] = 0.f; }

  // stage K rows r=w*8+i; LDS dest wave-uniform base (+lane*16B implicit);
  // global src chunk pre-swizzled l ^ (r&7) so logical chunk c sits at c^(r&7)
  #define STAGE(tile_)                                                       \
    { const int kk0 = (tile_) * KVB;                                         \
      _Pragma("unroll")                                                      \
      for (int i = 0; i < 8; i++){                                           \
        const int r = w*8 + i;                                               \
        const u16* src = E + ebase + (size_t)(kk0 + r) * EMBD                \
                           + ((l ^ (r & 7)) * 8);                            \
        gload_lds16(src, Klds + (size_t)r * EMBD);                           \
      } }

  STAGE(0)

  const int quad = l & 15, c8h = l >> 4;
  const int e7 = l15 & 7;

  for (int t = 0; t < NT; t++){
    const int k0 = t * KVB;
    __syncthreads();                     // B0: stage(t) drained; bufs free

    // ---- issue V row loads (consumed by Vt transpose after QKT) ----
    bf16x8 vr[2][4];
    #pragma unroll
    for (int h = 0; h < 2; h++){
      const int c8 = c8h + h*4;          // e-chunk 0..7 in wave's 64-e slice
      const u16* vp = E + ebase + (size_t)(k0 + quad*4) * EMBD + w*64 + c8*8;
      vr[h][0] = *(const bf16x8*)(vp);
      vr[h][1] = *(const bf16x8*)(vp +   EMBD);
      vr[h][2] = *(const bf16x8*)(vp + 2*EMBD);
      vr[h][3] = *(const bf16x8*)(vp + 3*EMBD);
    }

    // ---- QK^T: S[iq*16..+16][jq*32..+32] ----
    f32x4 s0 = (f32x4){0.f,0.f,0.f,0.f}, s1 = s0;
    {
      const int r0 = jq*32 + l15, r1 = r0 + 16;
      __builtin_amdgcn_s_setprio(1);
      #pragma unroll
      for (int ks = 0; ks < 16; ks++){
        const int c = ks*4 + lg;
        bf16x8 kb0 = *(const bf16x8*)&Klds[(size_t)r0 * EMBD + ((c ^ e7) * 8)];
        bf16x8 kb1 = *(const bf16x8*)&Klds[(size_t)r1 * EMBD + ((c ^ e7) * 8)];
        s0 = __builtin_amdgcn_mfma_f32_16x16x32_bf16(qf[ks], kb0, s0, 0, 0, 0);
        s1 = __builtin_amdgcn_mfma_f32_16x16x32_bf16(qf[ks], kb1, s1, 0, 0, 0);
      }
      __builtin_amdgcn_s_setprio(0);
    }
    #pragma unroll
    for (int rr = 0; rr < 4; rr++){
      Sbuf[iq*16 + lg*4 + rr][jq*32 +      l15] = s0[rr];
      Sbuf[iq*16 + lg*4 + rr][jq*32 + 16 + l15] = s1[rr];
    }

    // ---- V transpose into wave-private Vt (b64 writes, floor-phased) ----
    #pragma unroll
    for (int h = 0; h < 2; h++){
      const int c8 = c8h + h*4;
      #pragma unroll
      for (int i = 0; i < 8; i++){
        const int el = c8*8 + i;                       // e_local 0..63
        const int ch = (quad >> 1) ^ (el & 7);         // swizzled 16B chunk
        short4 sv; sv.x = vr[h][0][i]; sv.y = vr[h][1][i];
                   sv.z = vr[h][2][i]; sv.w = vr[h][3][i];
        *(short4*)&Vt[(size_t)w*4096 + el*64 + ch*8 + (quad&1)*4] = sv;
      }
    }

    __syncthreads();                     // B1: Sbuf + Vt complete; kb reads done

    // ---- stage K(t+1): overlaps softmax + PV, drained at next B0 ----
    if (t + 1 < NT) STAGE(t + 1)

    // ---- online softmax: thread = (row=tid>>3, cg=tid&7), 8 tok each ----
    {
      const int row = tid >> 3, cg = tid & 7;
      f32x4 sa = *(f32x4*)&Sbuf[row][cg*8];
      f32x4 sb = *(f32x4*)&Sbuf[row][cg*8 + 4];
      float mx = fmaxf(fmaxf(fmaxf(sa[0],sa[1]), fmaxf(sa[2],sa[3])),
                       fmaxf(fmaxf(sb[0],sb[1]), fmaxf(sb[2],sb[3])));
      #pragma unroll
      for (int d = 1; d < 8; d <<= 1) mx = fmaxf(mx, __shfl_xor(mx, d));
      const float mold = m_lds[row], lold = l_lds[row];
      const float mnew = fmaxf(mold, mx);
      float pp[8];
      #pragma unroll
      for (int i = 0; i < 4; i++) pp[i]   = __expf(sa[i] - mnew);
      #pragma unroll
      for (int i = 0; i < 4; i++) pp[4+i] = __expf(sb[i] - mnew);
      float sum = ((pp[0]+pp[1])+(pp[2]+pp[3])) + ((pp[4]+pp[5])+(pp[6]+pp[7]));
      #pragma unroll
      for (int d = 1; d < 8; d <<= 1) sum += __shfl_xor(sum, d);
      const float alpha = __expf(mold - mnew);   // -inf -> 0 on first tile
      if (cg == 0){
        m_lds[row] = mnew;
        l_lds[row] = lold * alpha + sum;
        a_lds[row] = alpha;
      }
      bf16x8 pv;
      #pragma unroll
      for (int i = 0; i < 8; i++) pv[i] = (short)f2bf(pp[i]);
      *(bf16x8*)&Ps[row][cg*8] = pv;
    }

    __syncthreads();                     // B2: Ps + alpha ready

    // ---- rescale O (skip when all alpha==1), then O += P V ----
    {
      f32x4 al[4];
      int need = 0;
      #pragma unroll
      for (int ip = 0; ip < 4; ip++){
        al[ip] = *(f32x4*)&a_lds[ip*16 + lg*4];
        need |= (al[ip][0] != 1.f) | (al[ip][1] != 1.f) |
                (al[ip][2] != 1.f) | (al[ip][3] != 1.f);
      }
      if (__any(need)){
        #pragma unroll
        for (int ip = 0; ip < 4; ip++)
          #pragma unroll
          for (int jp = 0; jp < 4; jp++)
            #pragma unroll
            for (int rr = 0; rr < 4; rr++) acc[ip][jp][rr] *= al[ip][rr];
      }
    }
    #pragma unroll
    for (int kt = 0; kt < 2; kt++){
      bf16x8 pa[4], vb[4];
      #pragma unroll
      for (int ip = 0; ip < 4; ip++)
        pa[ip] = *(const bf16x8*)&Ps[ip*16 + l15][kt*32 + lg*8];
      #pragma unroll
      for (int jp = 0; jp < 4; jp++){
        const int el = jp*16 + l15;                    // e_local
        const int ch = (kt*4 + lg) ^ (el & 7);
        vb[jp] = *(const bf16x8*)&Vt[(size_t)w*4096 + el*64 + ch*8];
      }
      __builtin_amdgcn_s_setprio(1);
      #pragma unroll
      for (int ip = 0; ip < 4; ip++)
        #pragma unroll
        for (int jp = 0; jp < 4; jp++)
          acc[ip][jp] = __builtin_amdgcn_mfma_f32_16x16x32_bf16(
                            pa[ip], vb[jp], acc[ip][jp], 0, 0, 0);
      __builtin_amdgcn_s_setprio(0);
    }
  }

  __syncthreads();
  // ---- epilogue: 1/l scaling, column max over 64 q-rows, write partial ----
  #pragma unroll
  for (int ip = 0; ip < 4; ip++){
    f32x4 lv = *(f32x4*)&l_lds[ip*16 + lg*4];
    f32x4 inv;
    #pragma unroll
    for (int rr = 0; rr < 4; rr++) inv[rr] = 1.f / lv[rr];
    #pragma unroll
    for (int jp = 0; jp < 4; jp++)
      #pragma unroll
      for (int rr = 0; rr < 4; rr++) acc[ip][jp][rr] *= inv[rr];
  }
  #pragma unroll
  for (int jp = 0; jp < 4; jp++){
    float cm = -INFINITY;
    #pragma unroll
    for (int ip = 0; ip < 4; ip++)
      #pragma unroll
      for (int rr = 0; rr < 4; rr++) cm = fmaxf(cm, acc[ip][jp][rr]);
    cm = fmaxf(cm, __shfl_xor(cm, 16));
    cm = fmaxf(cm, __shfl_xor(cm, 32));
    if (lg == 0)
      part[(size_t)(b*32 + qt) * EMBD + w*64 + jp*16 + l15] = cm;
  }
}

// ---------------------------------------------------------------------------
// Kernel 2: pooled[b][e] = max over 32 q-tiles; out[b][o] = pooled.W[o] + b[o]
// ---------------------------------------------------------------------------
__global__ __launch_bounds__(512) void k_final(const float* __restrict__ part,
                                               const float* __restrict__ Wm,
                                               const float* __restrict__ bias,
                                               float* __restrict__ out){
  __shared__ float pooled[EMBD];
  const int b = blockIdx.x, tid = threadIdx.x;
  float mx = -INFINITY;
  const float* pb = part + (size_t)b * 32 * EMBD + tid;
  #pragma unroll
  for (int qt = 0; qt < 32; qt++) mx = fmaxf(mx, pb[qt * EMBD]);
  pooled[tid] = mx;
  __syncthreads();
  const int w = tid >> 6, l = tid & 63;     // w = output index (8 waves)
  float sum = 0.f;
  #pragma unroll
  for (int m = 0; m < 8; m++)
    sum += pooled[l + m*64] * Wm[w*EMBD + l + m*64];
  #pragma unroll
  for (int d = 1; d < 64; d <<= 1) sum += __shfl_xor(sum, d);
  if (l == 0) out[b * NOUT + w] = sum + bias[w];
}

// ---------------------------------------------------------------------------
extern "C" void kernel_launch(void* const* d_in, const int* in_sizes, int n_in,
                              void* d_out, int out_size, void* d_ws, size_t ws_size,
                              hipStream_t stream){
  const int*   x    = (const int*)  d_in[0];   // [16,2048]
  const float* tab  = (const float*)d_in[1];   // [32000,512]
  const float* Wm   = (const float*)d_in[2];   // [8,512]
  const float* bias = (const float*)d_in[3];   // [8]
  float* out = (float*)d_out;                  // [16,8]

  // ws: E bf16 [16*2048,512] = 32MB, then partials [16][32][512] f32 = 1MB
  u16*   E    = (u16*)d_ws;
  float* part = (float*)((char*)d_ws + (size_t)32 * 1024 * 1024);

  k_embed<<<BATCH*SEQ/8, 512, 0, stream>>>(x, tab, E);
  k_attn <<<BATCH*(SEQ/QB), 512, 0, stream>>>(E, part);
  k_final<<<BATCH, 512, 0, stream>>>(part, Wm, bias, out);
}